// Round 1
// baseline (66.036 us; speedup 1.0000x reference)
//
#include <hip/hip_runtime.h>
#include <math.h>

#define N 256
#define H 128
#define E 64
#define K 4
#define M (N + 1)
#define WAVES 16
#define BLOCK (WAVES * 64)

// ---------------------------------------------------------------------------
// helpers
// ---------------------------------------------------------------------------
__device__ __forceinline__ float sigm(float x) {
    return __fdividef(1.0f, 1.0f + __expf(-x));
}

__device__ __forceinline__ float wave_sum(float v) {
#pragma unroll
    for (int d = 1; d < 64; d <<= 1) v += __shfl_xor(v, d, 64);
    return v;
}

// Bit-exact replication of cal_dist's per-pair math (numpy fp32, no FMA
// contraction: every op is an individually rounded IEEE op).
// Roles: (r = row index, c = col index), r < c.  Returns dist[r][c], dist[c][r].
__device__ __forceinline__ void pairdist(
    float a1x, float a1y, float a2x, float a2y,
    float g1x, float g1y, float g2x, float g2y,
    float baseR, float baseC, float& d_rc, float& d_cr)
{
    // dn = (a1x-a1x)*(g1y-g2y) - (a1y-a2y)*(g1x-g2x)  -> first term == 0
    float t  = __fmul_rn(__fsub_rn(a1y, a2y), __fsub_rn(g1x, g2x));
    float dn = -t;  // 0 - t is exact
    float ca = __fsub_rn(__fmul_rn(a1x, a2y), __fmul_rn(a1y, a2x));
    // gterm = g1x*g2y - g1x*g2x   (reference bug replicated)
    float gt = __fsub_rn(__fmul_rn(g1x, g2y), __fmul_rn(g1x, g2x));
    float n1 = __fsub_rn(__fmul_rn(ca, __fsub_rn(g1x, g2x)),
                         __fmul_rn(__fsub_rn(a1x, a2x), gt));
    // n2 uses (a1y - a2x)  (reference bug replicated)
    float n2 = __fsub_rn(__fmul_rn(ca, __fsub_rn(g1y, g2y)),
                         __fmul_rn(__fsub_rn(a1y, a2x), gt));
    float safe = (dn == 0.0f) ? 1.0f : dn;
    float p1 = __fdiv_rn(n1, safe);
    float p2 = __fdiv_rn(n2, safe);
    bool cond = (dn != 0.0f) &&
                (__fmul_rn(__fsub_rn(a1x, p1), __fsub_rn(p1, g1x)) > 0.0f);
    float dx1 = __fsub_rn(a1x, p1), dy1 = __fsub_rn(a1y, p2);
    float d1p = __fsqrt_rn(__fadd_rn(__fmul_rn(dx1, dx1), __fmul_rn(dy1, dy1)));
    float dx2 = __fsub_rn(a2x, p1), dy2 = __fsub_rn(a2y, p2);
    float d2p = __fsqrt_rn(__fadd_rn(__fmul_rn(dx2, dx2), __fmul_rn(dy2, dy2)));
    d_rc = cond ? d1p : baseR;
    d_cr = cond ? d2p : baseC;
}

// ---------------------------------------------------------------------------
// Kernel 1: precompute
//   blocks 0..N-1 : A1[i,f]=ha[i]@W1, A2[i,f]=ha[i]@W2, G2[i,f]=hg[i]@W2, base[i]
//   block  N      : u3=W_emb@W3, u4=W_emb@W4, cc=b_emb@(W3+W4)+b_gate,
//                   v_src[k]=W_gat[k]@a_src[k], v_dst[k]=W_gat[k]@a_dst[k]
// ---------------------------------------------------------------------------
__global__ __launch_bounds__(H) void gat_precompute(
    const float* __restrict__ ha, const float* __restrict__ hg,
    const float* __restrict__ goal, const float* __restrict__ action,
    const float* __restrict__ W_emb, const float* __restrict__ b_emb,
    const float* __restrict__ W_gate, const float* __restrict__ b_gate,
    const float* __restrict__ W_gat, const float* __restrict__ a_src,
    const float* __restrict__ a_dst,
    float* __restrict__ A1, float* __restrict__ A2, float* __restrict__ G2,
    float* __restrict__ u3, float* __restrict__ u4, float* __restrict__ cc,
    float* __restrict__ vsrc, float* __restrict__ vdst,
    float* __restrict__ baseArr)
{
    const int f = threadIdx.x;
    const int b = blockIdx.x;
    if (b < N) {
        float s1 = 0.0f, s2 = 0.0f, s3 = 0.0f;
#pragma unroll 4
        for (int g = 0; g < H; ++g) {
            float w1 = W_gate[g * H + f];
            float w2 = W_gate[(H + g) * H + f];
            float hv = ha[b * H + g];
            s1 += hv * w1;
            s2 += hv * w2;
            s3 += hg[b * H + g] * w2;
        }
        A1[b * H + f] = s1;
        A2[b * H + f] = s2;
        G2[b * H + f] = s3;
        if (f == 0) {
            float dx = __fsub_rn(action[b * 2 + 0], goal[b * 2 + 0]);
            float dy = __fsub_rn(action[b * 2 + 1], goal[b * 2 + 1]);
            baseArr[b] = __fsqrt_rn(__fadd_rn(__fmul_rn(dx, dx), __fmul_rn(dy, dy)));
        }
    } else {
        float s3 = 0.0f, s4 = 0.0f, sc = 0.0f;
#pragma unroll 4
        for (int e = 0; e < E; ++e) {
            float w3 = W_gate[(2 * H + e) * H + f];
            float w4 = W_gate[(2 * H + E + e) * H + f];
            float we = W_emb[e];
            s3 += we * w3;
            s4 += we * w4;
            sc += b_emb[e] * (w3 + w4);
        }
        u3[f] = s3;
        u4[f] = s4;
        cc[f] = sc + b_gate[f];
#pragma unroll
        for (int k = 0; k < K; ++k) {
            float vs = 0.0f, vd = 0.0f;
#pragma unroll 4
            for (int o = 0; o < H; ++o) {
                float w = W_gat[(k * H + f) * H + o];
                vs += w * a_src[k * H + o];
                vd += w * a_dst[k * H + o];
            }
            vsrc[k * H + f] = vs;
            vdst[k * H + f] = vd;
        }
    }
}

// ---------------------------------------------------------------------------
// Kernel 2: main — one block per output row i, 16 waves, online softmax over j
// ---------------------------------------------------------------------------
__global__ __launch_bounds__(BLOCK) void gat_main(
    const float* __restrict__ ha, const float* __restrict__ hg,
    const float* __restrict__ W_gat, const float* __restrict__ gat_bias,
    const float* __restrict__ A1, const float* __restrict__ A2,
    const float* __restrict__ G2,
    const float* __restrict__ u3a, const float* __restrict__ u4a,
    const float* __restrict__ cca,
    const float* __restrict__ vsrc, const float* __restrict__ vdst,
    const float* __restrict__ baseArr,
    const float* __restrict__ goal, const float* __restrict__ action,
    float* __restrict__ out)
{
    const int i    = blockIdx.x;
    const int tid  = threadIdx.x;
    const int wid  = tid >> 6;
    const int lane = tid & 63;
    const int f0   = lane * 2;

    __shared__ float2 sAct[N];
    __shared__ float2 sGoal[N];
    __shared__ float  sBase[N];
    __shared__ float  sW[WAVES][K][H];
    __shared__ float  sM[WAVES][K];
    __shared__ float  sL[WAVES][K];
    __shared__ float  sWfin[K][H];
    __shared__ float  sPart[8][H];

    for (int t = tid; t < N; t += BLOCK) {
        sAct[t]  = ((const float2*)action)[t];
        sGoal[t] = ((const float2*)goal)[t];
        sBase[t] = baseArr[t];
    }
    __syncthreads();

    // per-lane constants (2 features per lane)
    const float2 a1v = *(const float2*)&A1[i * H + f0];
    const float2 haI = *(const float2*)&ha[i * H + f0];
    const float2 hgI = *(const float2*)&hg[i * H + f0];
    const float2 g2v = *(const float2*)&G2[i * H + f0];
    const float2 u3  = *(const float2*)&u3a[f0];
    const float2 u4  = *(const float2*)&u4a[f0];
    const float2 cc  = *(const float2*)&cca[f0];
    float2 vd[K];
#pragma unroll
    for (int k = 0; k < K; ++k) vd[k] = *(const float2*)&vdst[k * H + f0];

    // s_const[k] = ha[i] . v_src[k]   (row logit; diagonal gat_in = ha[i])
    float sc[K];
#pragma unroll
    for (int k = 0; k < K; ++k) {
        float2 vs = *(const float2*)&vsrc[k * H + f0];
        sc[k] = wave_sum(haI.x * vs.x + haI.y * vs.y);
    }

    const float2 actI  = sAct[i];
    const float2 goalI = sGoal[i];
    const float  baseI = sBase[i];

    // online softmax state (per wave; f-dim split 2/lane)
    float m_[K], l_[K], w0[K], w1[K];
#pragma unroll
    for (int k = 0; k < K; ++k) { m_[k] = -INFINITY; l_[k] = 0.f; w0[k] = 0.f; w1[k] = 0.f; }

    for (int j = wid; j < M; j += WAVES) {
        float2 gin;
        if (j == N) {
            // goal row: hg[i] * sigmoid(A1 + G2 + base_i*(u3+u4) + cc)
            float tx = a1v.x + g2v.x + baseI * (u3.x + u4.x) + cc.x;
            float ty = a1v.y + g2v.y + baseI * (u3.y + u4.y) + cc.y;
            gin.x = hgI.x * sigm(tx);
            gin.y = hgI.y * sigm(ty);
        } else if (j == i) {
            gin = haI;  // diagonal: ungated ha[i]
        } else {
            float2 actJ = sAct[j], goalJ = sGoal[j];
            float d_ij, d_ji;
            if (i < j) {
                pairdist(actI.x, actI.y, actJ.x, actJ.y,
                         goalI.x, goalI.y, goalJ.x, goalJ.y,
                         baseI, sBase[j], d_ij, d_ji);
            } else {
                pairdist(actJ.x, actJ.y, actI.x, actI.y,
                         goalJ.x, goalJ.y, goalI.x, goalI.y,
                         sBase[j], baseI, d_ji, d_ij);
            }
            float2 a2v = *(const float2*)&A2[j * H + f0];
            float2 haJ = *(const float2*)&ha[j * H + f0];
            float tx = a1v.x + a2v.x + d_ij * u3.x + d_ji * u4.x + cc.x;
            float ty = a1v.y + a2v.y + d_ij * u3.y + d_ji * u4.y + cc.y;
            gin.x = haJ.x * sigm(tx);
            gin.y = haJ.y * sigm(ty);
        }

        // dst logits: full-wave reduction of gin . v_dst[k]
        float dd[K];
#pragma unroll
        for (int k = 0; k < K; ++k)
            dd[k] = wave_sum(gin.x * vd[k].x + gin.y * vd[k].y);

#pragma unroll
        for (int k = 0; k < K; ++k) {
            float logit = sc[k] + dd[k];
            logit = (logit >= 0.0f) ? logit : 0.2f * logit;  // leaky_relu
            if (logit > m_[k]) {  // wave-uniform branch
                float scale = __expf(m_[k] - logit);
                l_[k] *= scale; w0[k] *= scale; w1[k] *= scale;
                m_[k] = logit;
            }
            float p = __expf(logit - m_[k]);
            l_[k] += p;
            w0[k] += p * gin.x;
            w1[k] += p * gin.y;
        }
    }

    // dump per-wave partial softmax states
#pragma unroll
    for (int k = 0; k < K; ++k) {
        sW[wid][k][f0]     = w0[k];
        sW[wid][k][f0 + 1] = w1[k];
        if (lane == 0) { sM[wid][k] = m_[k]; sL[wid][k] = l_[k]; }
    }
    __syncthreads();

    // merge 16 wave-partials -> normalized weighted sum  wfin[k][f]
    if (tid < H) {
        const int f = tid;
#pragma unroll
        for (int k = 0; k < K; ++k) {
            float Mx = -INFINITY;
#pragma unroll
            for (int w = 0; w < WAVES; ++w) Mx = fmaxf(Mx, sM[w][k]);
            float L = 0.0f, W = 0.0f;
#pragma unroll
            for (int w = 0; w < WAVES; ++w) {
                float s = __expf(sM[w][k] - Mx);
                L += s * sL[w][k];
                W += s * sW[w][k][f];
            }
            sWfin[k][f] = W / L;
        }
    }
    __syncthreads();

    // epilogue: out[f] = elu( 0.25 * sum_k wfin[k] @ W_gat[k] [.,f] + bias[f] )
    {
        const int f = tid & (H - 1);
        const int s = tid >> 7;  // 0..7, g-slice of 16
        float acc = 0.0f;
#pragma unroll
        for (int k = 0; k < K; ++k) {
            const int g0 = s * 16;
#pragma unroll
            for (int g = 0; g < 16; ++g)
                acc += sWfin[k][g0 + g] * W_gat[(k * H + g0 + g) * H + f];
        }
        sPart[s][f] = acc;
    }
    __syncthreads();

    if (tid < H) {
        float acc = 0.0f;
#pragma unroll
        for (int s = 0; s < 8; ++s) acc += sPart[s][tid];
        float val = 0.25f * acc + gat_bias[tid];
        out[i * H + tid] = (val > 0.0f) ? val : expm1f(val);  // elu, alpha=1
    }
}

// ---------------------------------------------------------------------------
extern "C" void kernel_launch(void* const* d_in, const int* in_sizes, int n_in,
                              void* d_out, int out_size, void* d_ws, size_t ws_size,
                              hipStream_t stream)
{
    const float* ha       = (const float*)d_in[0];
    const float* hg       = (const float*)d_in[1];
    const float* goal     = (const float*)d_in[2];
    const float* action   = (const float*)d_in[3];
    const float* W_emb    = (const float*)d_in[4];
    const float* b_emb    = (const float*)d_in[5];
    const float* W_gate   = (const float*)d_in[6];
    const float* b_gate   = (const float*)d_in[7];
    const float* W_gat    = (const float*)d_in[8];
    const float* a_src    = (const float*)d_in[9];
    const float* a_dst    = (const float*)d_in[10];
    const float* gat_bias = (const float*)d_in[11];

    float* ws   = (float*)d_ws;
    float* A1   = ws;                    // N*H
    float* A2   = A1 + N * H;            // N*H
    float* G2   = A2 + N * H;            // N*H
    float* u3   = G2 + N * H;            // H
    float* u4   = u3 + H;                // H
    float* cc   = u4 + H;                // H
    float* vs   = cc + H;                // K*H
    float* vd   = vs + K * H;            // K*H
    float* base = vd + K * H;            // N

    hipLaunchKernelGGL(gat_precompute, dim3(N + 1), dim3(H), 0, stream,
                       ha, hg, goal, action, W_emb, b_emb, W_gate, b_gate,
                       W_gat, a_src, a_dst,
                       A1, A2, G2, u3, u4, cc, vs, vd, base);

    hipLaunchKernelGGL(gat_main, dim3(N), dim3(BLOCK), 0, stream,
                       ha, hg, W_gat, gat_bias,
                       A1, A2, G2, u3, u4, cc, vs, vd, base,
                       goal, action, (float*)d_out);
}

// Round 2
// 34.431 us; speedup vs baseline: 1.9179x; 1.9179x over previous
//
#include <hip/hip_runtime.h>
#include <math.h>

#define N 256
#define H 128
#define E 64
#define K 4
#define M (N + 1)
#define WAVES 16
#define BLOCK (WAVES * 64)

// ---------------------------------------------------------------------------
// helpers
// ---------------------------------------------------------------------------
__device__ __forceinline__ float sigm(float x) {
    return __fdividef(1.0f, 1.0f + __expf(-x));
}

__device__ __forceinline__ float wave_sum(float v) {
#pragma unroll
    for (int d = 1; d < 64; d <<= 1) v += __shfl_xor(v, d, 64);
    return v;
}

__device__ __forceinline__ float readlane_f(float v, int l) {
    return __uint_as_float(__builtin_amdgcn_readlane(__float_as_uint(v), l));
}

// Bit-exact replication of cal_dist's per-pair math (numpy fp32, no FMA
// contraction). Roles: r = row idx, c = col idx, r < c. Returns d[r][c], d[c][r].
__device__ __forceinline__ void pairdist(
    float a1x, float a1y, float a2x, float a2y,
    float g1x, float g1y, float g2x, float g2y,
    float baseR, float baseC, float& d_rc, float& d_cr)
{
    float t  = __fmul_rn(__fsub_rn(a1y, a2y), __fsub_rn(g1x, g2x));
    float dn = -t;  // (a1x-a1x)*(...) == 0 exactly
    float ca = __fsub_rn(__fmul_rn(a1x, a2y), __fmul_rn(a1y, a2x));
    float gt = __fsub_rn(__fmul_rn(g1x, g2y), __fmul_rn(g1x, g2x));  // ref bug kept
    float n1 = __fsub_rn(__fmul_rn(ca, __fsub_rn(g1x, g2x)),
                         __fmul_rn(__fsub_rn(a1x, a2x), gt));
    float n2 = __fsub_rn(__fmul_rn(ca, __fsub_rn(g1y, g2y)),
                         __fmul_rn(__fsub_rn(a1y, a2x), gt));        // ref bug kept
    float safe = (dn == 0.0f) ? 1.0f : dn;
    float p1 = __fdiv_rn(n1, safe);
    float p2 = __fdiv_rn(n2, safe);
    bool cond = (dn != 0.0f) &&
                (__fmul_rn(__fsub_rn(a1x, p1), __fsub_rn(p1, g1x)) > 0.0f);
    float dx1 = __fsub_rn(a1x, p1), dy1 = __fsub_rn(a1y, p2);
    float d1p = __fsqrt_rn(__fadd_rn(__fmul_rn(dx1, dx1), __fmul_rn(dy1, dy1)));
    float dx2 = __fsub_rn(a2x, p1), dy2 = __fsub_rn(a2y, p2);
    float d2p = __fsqrt_rn(__fadd_rn(__fmul_rn(dx2, dx2), __fmul_rn(dy2, dy2)));
    d_rc = cond ? d1p : baseR;
    d_cr = cond ? d2p : baseC;
}

// ---------------------------------------------------------------------------
// Kernel 1: precompute (265 blocks x 256 threads)
// ---------------------------------------------------------------------------
__global__ __launch_bounds__(256) void gat_precompute(
    const float* __restrict__ ha, const float* __restrict__ hg,
    const float* __restrict__ goal, const float* __restrict__ action,
    const float* __restrict__ W_emb, const float* __restrict__ b_emb,
    const float* __restrict__ W_gate, const float* __restrict__ b_gate,
    const float* __restrict__ W_gat, const float* __restrict__ a_src,
    const float* __restrict__ a_dst,
    float* __restrict__ A1, float* __restrict__ A2, float* __restrict__ G2,
    float* __restrict__ u3, float* __restrict__ u4, float* __restrict__ cc,
    float* __restrict__ vsrc, float* __restrict__ vdst,
    float* __restrict__ baseArr)
{
    const int tid = threadIdx.x;
    const int b   = blockIdx.x;

    if (b < N) {
        __shared__ float sP[2][3][H];
        const int f    = tid & (H - 1);
        const int half = tid >> 7;
        const int g0   = half * 64;
        float s1 = 0.f, s2 = 0.f, s3 = 0.f;
#pragma unroll 8
        for (int g = 0; g < 64; ++g) {
            const int gg = g0 + g;
            float w1 = W_gate[gg * H + f];
            float w2 = W_gate[(H + gg) * H + f];
            float av = ha[b * H + gg];
            float gv = hg[b * H + gg];
            s1 += av * w1;
            s2 += av * w2;
            s3 += gv * w2;
        }
        sP[half][0][f] = s1;
        sP[half][1][f] = s2;
        sP[half][2][f] = s3;
        __syncthreads();
        if (half == 0) {
            A1[b * H + f] = sP[0][0][f] + sP[1][0][f];
            A2[b * H + f] = sP[0][1][f] + sP[1][1][f];
            G2[b * H + f] = sP[0][2][f] + sP[1][2][f];
        }
        if (tid == 0) {
            float dx = __fsub_rn(action[b * 2 + 0], goal[b * 2 + 0]);
            float dy = __fsub_rn(action[b * 2 + 1], goal[b * 2 + 1]);
            baseArr[b] = __fsqrt_rn(__fadd_rn(__fmul_rn(dx, dx), __fmul_rn(dy, dy)));
        }
    } else if (b < N + 8) {
        const int bb   = b - N;
        const int wid  = tid >> 6;
        const int lane = tid & 63;
        const int k    = bb >> 1;   // fixed per block
        const float2 as = *(const float2*)&a_src[k * H + lane * 2];
        const float2 ad = *(const float2*)&a_dst[k * H + lane * 2];
#pragma unroll
        for (int it = 0; it < 16; ++it) {
            const int pair = bb * 64 + wid * 16 + it;
            const int f    = pair & (H - 1);
            const float2 w = *(const float2*)&W_gat[(k * H + f) * H + lane * 2];
            float vs = wave_sum(w.x * as.x + w.y * as.y);
            float vv = wave_sum(w.x * ad.x + w.y * ad.y);
            if (lane == 0) {
                vsrc[k * H + f] = vs;
                vdst[k * H + f] = vv;
            }
        }
    } else {
        if (tid < H) {
            float s3 = 0.f, s4 = 0.f, scc = 0.f;
#pragma unroll 8
            for (int e = 0; e < E; ++e) {
                float w3 = W_gate[(2 * H + e) * H + tid];
                float w4 = W_gate[(2 * H + E + e) * H + tid];
                float we = W_emb[e];
                float be = b_emb[e];
                s3  += we * w3;
                s4  += we * w4;
                scc += be * (w3 + w4);
            }
            u3[tid] = s3;
            u4[tid] = s4;
            cc[tid] = scc + b_gate[tid];
        }
    }
}

// ---------------------------------------------------------------------------
// Kernel 2: main — one block per output row i, 16 waves
// ---------------------------------------------------------------------------
__global__ __launch_bounds__(BLOCK) void gat_main(
    const float* __restrict__ ha, const float* __restrict__ hg,
    const float* __restrict__ W_gat, const float* __restrict__ gat_bias,
    const float* __restrict__ A1, const float* __restrict__ A2,
    const float* __restrict__ G2,
    const float* __restrict__ u3a, const float* __restrict__ u4a,
    const float* __restrict__ cca,
    const float* __restrict__ vsrc, const float* __restrict__ vdst,
    const float* __restrict__ baseArr,
    const float* __restrict__ goal, const float* __restrict__ action,
    float* __restrict__ out)
{
    const int i    = blockIdx.x;
    const int tid  = threadIdx.x;
    const int wid  = tid >> 6;
    const int lane = tid & 63;
    const int f0   = lane * 2;
    const int kown = lane & 3;

    __shared__ float2 sAct[N];
    __shared__ float2 sGoal[N];
    __shared__ float  sBase[N];
    __shared__ float  sDij[M];
    __shared__ float  sDji[M];
    __shared__ float  sW[WAVES][K][H];
    __shared__ float  sM[WAVES];
    __shared__ float  sL[WAVES][K];
    __shared__ float  sWfin[K][H];
    __shared__ float  sPart[8][H];

    for (int t = tid; t < N; t += BLOCK) {
        sAct[t]  = ((const float2*)action)[t];
        sGoal[t] = ((const float2*)goal)[t];
        sBase[t] = baseArr[t];
    }
    __syncthreads();

    // pass 0: all 257 distance pairs, one per thread (bit-identical pairdist)
    if (tid < M) {
        const int j = tid;
        float dij = 0.f, dji = 0.f;
        if (j != i && j != N) {
            const float2 aI = sAct[i], gI = sGoal[i];
            const float2 aJ = sAct[j], gJ = sGoal[j];
            if (i < j)
                pairdist(aI.x, aI.y, aJ.x, aJ.y, gI.x, gI.y, gJ.x, gJ.y,
                         sBase[i], sBase[j], dij, dji);
            else
                pairdist(aJ.x, aJ.y, aI.x, aI.y, gJ.x, gJ.y, gI.x, gI.y,
                         sBase[j], sBase[i], dji, dij);
        }
        sDij[j] = dij;
        sDji[j] = dji;
    }

    // per-lane constants (2 features per lane)
    const float2 a1v = *(const float2*)&A1[i * H + f0];
    const float2 haI = *(const float2*)&ha[i * H + f0];
    const float2 hgI = *(const float2*)&hg[i * H + f0];
    const float2 g2v = *(const float2*)&G2[i * H + f0];
    const float2 u3  = *(const float2*)&u3a[f0];
    const float2 u4  = *(const float2*)&u4a[f0];
    const float2 cc  = *(const float2*)&cca[f0];
    const float2 a1cc = make_float2(a1v.x + cc.x, a1v.y + cc.y);
    float2 vd[K];
#pragma unroll
    for (int k = 0; k < K; ++k) vd[k] = *(const float2*)&vdst[k * H + f0];

    // sc[k] = ha[i] . v_src[k]; keep only own-k copy per lane
    float scOwn;
    {
        float sc0, sc1, sc2, sc3;
        {
            float2 vs = *(const float2*)&vsrc[0 * H + f0];
            sc0 = wave_sum(haI.x * vs.x + haI.y * vs.y);
        }
        {
            float2 vs = *(const float2*)&vsrc[1 * H + f0];
            sc1 = wave_sum(haI.x * vs.x + haI.y * vs.y);
        }
        {
            float2 vs = *(const float2*)&vsrc[2 * H + f0];
            sc2 = wave_sum(haI.x * vs.x + haI.y * vs.y);
        }
        {
            float2 vs = *(const float2*)&vsrc[3 * H + f0];
            sc3 = wave_sum(haI.x * vs.x + haI.y * vs.y);
        }
        scOwn = sc0;
        if (kown == 1) scOwn = sc1;
        else if (kown == 2) scOwn = sc2;
        else if (kown == 3) scOwn = sc3;
    }

    const float baseI = sBase[i];
    __syncthreads();   // sDij/sDji ready

    // online softmax state: shared max m_ (wave-uniform), per-lane l_ (own k),
    // per-lane w accumulators for all k at this lane's 2 features
    float m_ = -INFINITY, l_ = 0.f;
    float w0[K], w1[K];
#pragma unroll
    for (int k = 0; k < K; ++k) { w0[k] = 0.f; w1[k] = 0.f; }

    int j = wid;
    float2 a2v, haJ;
    {
        const int jc = (j < N) ? j : 0;
        a2v = *(const float2*)&A2[jc * H + f0];
        haJ = *(const float2*)&ha[jc * H + f0];
    }

    for (; j < M; j += WAVES) {
        // prefetch next iteration's rows across this iteration's compute
        const int jn = j + WAVES;
        float2 a2n = make_float2(0.f, 0.f), han = make_float2(0.f, 0.f);
        if (jn < M) {
            const int jc = (jn < N) ? jn : 0;
            a2n = *(const float2*)&A2[jc * H + f0];
            han = *(const float2*)&ha[jc * H + f0];
        }

        float2 gin;
        if (j == N) {
            float tx = a1cc.x + g2v.x + baseI * (u3.x + u4.x);
            float ty = a1cc.y + g2v.y + baseI * (u3.y + u4.y);
            gin.x = hgI.x * sigm(tx);
            gin.y = hgI.y * sigm(ty);
        } else if (j == i) {
            gin = haI;
        } else {
            const float dij = sDij[j];
            const float dji = sDji[j];
            float tx = a1cc.x + a2v.x + dij * u3.x + dji * u4.x;
            float ty = a1cc.y + a2v.y + dij * u3.y + dji * u4.y;
            gin.x = haJ.x * sigm(tx);
            gin.y = haJ.y * sigm(ty);
        }

        // per-lane partial dot for each k
        float q0 = gin.x * vd[0].x + gin.y * vd[0].y;
        float q1 = gin.x * vd[1].x + gin.y * vd[1].y;
        float q2 = gin.x * vd[2].x + gin.y * vd[2].y;
        float q3 = gin.x * vd[3].x + gin.y * vd[3].y;

        // k-transposed butterfly: lane l ends with dd[k = l&3]
        const bool b1 = lane & 1;
        float aA = b1 ? q1 : q0, aB = b1 ? q0 : q1;
        aA += __shfl_xor(aB, 1, 64);
        float cA = b1 ? q3 : q2, cB = b1 ? q2 : q3;
        cA += __shfl_xor(cB, 1, 64);
        const bool b2 = lane & 2;
        float eA = b2 ? cA : aA, eB = b2 ? aA : cA;
        eA += __shfl_xor(eB, 2, 64);
        eA += __shfl_xor(eA, 4, 64);
        eA += __shfl_xor(eA, 8, 64);
        eA += __shfl_xor(eA, 16, 64);
        eA += __shfl_xor(eA, 32, 64);

        float t     = scOwn + eA;
        float logit = (t >= 0.0f) ? t : 0.2f * t;   // leaky_relu

        // wave-uniform max over the 4 k's
        float mm = fmaxf(logit, __shfl_xor(logit, 1, 64));
        mm = fmaxf(mm, __shfl_xor(mm, 2, 64));
        if (mm > m_) {                               // wave-uniform branch
            const float s = __expf(m_ - mm);
            l_ *= s;
#pragma unroll
            for (int k = 0; k < K; ++k) { w0[k] *= s; w1[k] *= s; }
            m_ = mm;
        }
        const float p = __expf(logit - m_);
        l_ += p;

        const float p0 = readlane_f(p, 0);
        const float p1 = readlane_f(p, 1);
        const float p2 = readlane_f(p, 2);
        const float p3 = readlane_f(p, 3);
        w0[0] += p0 * gin.x;  w1[0] += p0 * gin.y;
        w0[1] += p1 * gin.x;  w1[1] += p1 * gin.y;
        w0[2] += p2 * gin.x;  w1[2] += p2 * gin.y;
        w0[3] += p3 * gin.x;  w1[3] += p3 * gin.y;

        a2v = a2n;
        haJ = han;
    }

    // dump per-wave partials
#pragma unroll
    for (int k = 0; k < K; ++k)
        *(float2*)&sW[wid][k][f0] = make_float2(w0[k], w1[k]);
    if (lane == 0) sM[wid] = m_;
    if (lane < K)  sL[wid][lane] = l_;
    __syncthreads();

    // merge 16 wave-partials (single shared max per wave)
    if (tid < H) {
        const int f = tid;
        float Mx = -INFINITY;
#pragma unroll
        for (int w = 0; w < WAVES; ++w) Mx = fmaxf(Mx, sM[w]);
        float sfac[WAVES];
#pragma unroll
        for (int w = 0; w < WAVES; ++w) sfac[w] = __expf(sM[w] - Mx);
#pragma unroll
        for (int k = 0; k < K; ++k) {
            float L = 0.f, W = 0.f;
#pragma unroll
            for (int w = 0; w < WAVES; ++w) {
                L += sfac[w] * sL[w][k];
                W += sfac[w] * sW[w][k][f];
            }
            sWfin[k][f] = W / L;
        }
    }
    __syncthreads();

    // epilogue: out[f] = elu( 0.25 * sum_k wfin[k] @ W_gat[k][:,f] + bias[f] )
    {
        const int f = tid & (H - 1);
        const int s = tid >> 7;   // 0..7 -> g-slice of 16
        float acc = 0.0f;
#pragma unroll
        for (int k = 0; k < K; ++k) {
            const int g0 = s * 16;
#pragma unroll
            for (int g = 0; g < 16; ++g)
                acc += sWfin[k][g0 + g] * W_gat[(k * H + g0 + g) * H + f];
        }
        sPart[s][f] = acc;
    }
    __syncthreads();

    if (tid < H) {
        float acc = 0.0f;
#pragma unroll
        for (int s = 0; s < 8; ++s) acc += sPart[s][tid];
        float val = 0.25f * acc + gat_bias[tid];
        out[i * H + tid] = (val > 0.0f) ? val : expm1f(val);
    }
}

// ---------------------------------------------------------------------------
extern "C" void kernel_launch(void* const* d_in, const int* in_sizes, int n_in,
                              void* d_out, int out_size, void* d_ws, size_t ws_size,
                              hipStream_t stream)
{
    const float* ha       = (const float*)d_in[0];
    const float* hg       = (const float*)d_in[1];
    const float* goal     = (const float*)d_in[2];
    const float* action   = (const float*)d_in[3];
    const float* W_emb    = (const float*)d_in[4];
    const float* b_emb    = (const float*)d_in[5];
    const float* W_gate   = (const float*)d_in[6];
    const float* b_gate   = (const float*)d_in[7];
    const float* W_gat    = (const float*)d_in[8];
    const float* a_src    = (const float*)d_in[9];
    const float* a_dst    = (const float*)d_in[10];
    const float* gat_bias = (const float*)d_in[11];

    float* ws   = (float*)d_ws;
    float* A1   = ws;                    // N*H
    float* A2   = A1 + N * H;            // N*H
    float* G2   = A2 + N * H;            // N*H
    float* u3   = G2 + N * H;            // H
    float* u4   = u3 + H;                // H
    float* cc   = u4 + H;                // H
    float* vs   = cc + H;                // K*H
    float* vd   = vs + K * H;            // K*H
    float* base = vd + K * H;            // N

    hipLaunchKernelGGL(gat_precompute, dim3(N + 9), dim3(256), 0, stream,
                       ha, hg, goal, action, W_emb, b_emb, W_gate, b_gate,
                       W_gat, a_src, a_dst,
                       A1, A2, G2, u3, u4, cc, vs, vd, base);

    hipLaunchKernelGGL(gat_main, dim3(N), dim3(BLOCK), 0, stream,
                       ha, hg, W_gat, gat_bias,
                       A1, A2, G2, u3, u4, cc, vs, vd, base,
                       goal, action, (float*)d_out);
}